// Round 6
// baseline (140.301 us; speedup 1.0000x reference)
//
#include <hip/hip_runtime.h>
#include <stdint.h>

#define BS 7
#define HM 50
#define WM 50
#define HH 56
#define WW 56
#define PLANE_IN  2500             // 50*50
#define PLANE_OUT 3136             // 56*56
#define NPLANES   16384            // 64*256
#define COUNT_M   51380224.0f      // 64*256*56*56 = 49*2^20, exact fp32
#define PPB       8                // planes per block
#define NBLOCKS   (NPLANES / PPB)  // 2048

typedef unsigned long long u64;

// Kernel 1 (ballot-v2): 2048 blocks x 4 waves x 2 planes/wave.
// Coalesced full-wave loads (64 consecutive floats = 256B/inst, the pattern
// the 7TB/s fill kernel proves out). One __ballot (= one v_cmp) per 64-pixel
// window; 40 window ballots stashed register-resident via lane-select; each
// lane r<50 gathers its row bits with 2 shfl; row dilation in-register;
// column dilation = 3-step shfl_up prefix-OR. NO LDS atomics (round-4 K1's
// ~4.1M DS-pipe atomicOr = ~50us), NO partial-wave loads (round-5's mistake).
__global__ __launch_bounds__(256) void dropblock_dilate(
    const float* __restrict__ mask,
    u64* __restrict__ bitmap,
    unsigned* __restrict__ counts)
{
    __shared__ unsigned wsum[4];

    const int tid  = threadIdx.x;
    const int lane = tid & 63;
    const int wave = tid >> 6;

    unsigned pc_total = 0;

    for (int s = 0; s < 2; ++s) {
        const int plane_local = 2 * wave + s;  // 0..7
        const float* mp =
            mask + ((size_t)blockIdx.x * PPB + plane_local) * PLANE_IN;

        // 40 windows of 64 pixels cover the 2500-pixel plane.
        u64 bb = 0;  // lane i keeps ballot of window i (i < 40)
#pragma unroll
        for (int i = 0; i < 40; ++i) {
            const int idx = 64 * i + lane;
            float m = (idx < PLANE_IN) ? mp[idx] : 0.0f;
            u64 b = __ballot(m != 0.0f);
            if (lane == i) bb = b;
        }

        // Lane r<50 assembles row r's 50 seed bits from 2 stashed ballots.
        const int start = 50 * lane;
        const int j0 = start >> 6;             // <=49; ballots >=40 are 0
        const int off = start & 63;
        const u64 b0 = __shfl(bb, j0);
        const u64 b1 = __shfl(bb, (j0 + 1 < 64) ? j0 + 1 : 63);
        u64 row = b0 >> off;
        if (off) row |= b1 << (64 - off);
        row &= (1ULL << 50) - 1ULL;
        if (lane >= HM) row = 0ULL;

        // Row dilation: bit w -> bits w..w+6.
        u64 d = row | (row << 1);
        d |= d << 2;
        d |= d << 3;

        // Column dilation: lane h ORs rows h-6..h (window 2 -> 4 -> 7).
        d |= __shfl_up(d, 1);   // out-of-range shfl_up returns own value: OR idempotent
        d |= __shfl_up(d, 2);
        d |= __shfl_up(d, 3);

        if (lane < HH) {
            u64 keep = ~d & ((1ULL << 56) - 1ULL);
            bitmap[(size_t)blockIdx.x * (PPB * HH) + plane_local * HH + lane] = keep;
            pc_total += (unsigned)__popcll(keep);
        }
    }

#pragma unroll
    for (int off = 32; off; off >>= 1) pc_total += __shfl_down(pc_total, off, 64);
    if (lane == 0) wsum[wave] = pc_total;
    __syncthreads();
    if (tid == 0) counts[blockIdx.x] = wsum[0] + wsum[1] + wsum[2] + wsum[3];
}

// Kernel 2 (split-phase): issue prologue loads -> unconditional zero-stream
// of all output (pure fill pattern, no dependent loads in the loop -- the
// round-4 version stalled ~900cy on a scattered x fetch inside nearly every
// store iteration) -> barrier -> rewrite only the ~4% kept words.
// Same thread owns word j in both loops; barrier orders the two stores.
__global__ __launch_bounds__(256) void dropblock_scale(
    const float* __restrict__ x,
    const u64* __restrict__ bitmap,
    const unsigned* __restrict__ counts,
    float* __restrict__ out)
{
    __shared__ u64 bitsLDS[PPB * HH];  // 448 words
    __shared__ unsigned wsum[4];
    __shared__ float s_scale;

    const int tid = threadIdx.x;

    // Issue all prologue loads up front; they complete under the zero-stream.
    const u64* bmp = bitmap + (size_t)blockIdx.x * (PPB * HH);
    const u64 bm0 = bmp[tid];
    const u64 bm1 = (tid < PPB * HH - 256) ? bmp[256 + tid] : 0ULL;
    const uint4* cp = reinterpret_cast<const uint4*>(counts);  // 512 uint4
    const uint4 ca = cp[tid];
    const uint4 cb = cp[tid + 256];

    // Phase A: zero-stream 6272 contiguous float4 stores (fill-kernel pattern).
    const size_t fbase = (size_t)blockIdx.x * (PPB * PLANE_OUT / 4);
    float4* op = reinterpret_cast<float4*>(out) + fbase;
    const float4 z = {0.f, 0.f, 0.f, 0.f};
    for (int j = tid; j < PPB * PLANE_OUT / 4; j += 256) op[j] = z;

    // Stash bitmap + reduce the 2048 per-block counts -> scale.
    bitsLDS[tid] = bm0;
    if (tid < PPB * HH - 256) bitsLDS[256 + tid] = bm1;
    unsigned s = ca.x + ca.y + ca.z + ca.w + cb.x + cb.y + cb.z + cb.w;
#pragma unroll
    for (int off = 32; off; off >>= 1) s += __shfl_down(s, off, 64);
    if ((tid & 63) == 0) wsum[tid >> 6] = s;
    __syncthreads();
    if (tid == 0)
        s_scale = COUNT_M / (float)(wsum[0] + wsum[1] + wsum[2] + wsum[3]);
    __syncthreads();

    // Phase B: rewrite kept words only (~1 per thread on average).
    const float scale = s_scale;
    const float4* xp = reinterpret_cast<const float4*>(x) + fbase;
    for (int j = tid; j < PPB * PLANE_OUT / 4; j += 256) {
        const int wword = j / 14;              // 14 float4 per 56-pixel row
        const int q = j - 14 * wword;
        const unsigned m4 = (unsigned)((bitsLDS[wword] >> (4 * q)) & 0xFULL);
        if (m4) {
            float4 v = xp[j];
            float4 o;
            o.x = (m4 & 1u) ? v.x * scale : 0.f;
            o.y = (m4 & 2u) ? v.y * scale : 0.f;
            o.z = (m4 & 4u) ? v.z * scale : 0.f;
            o.w = (m4 & 8u) ? v.w * scale : 0.f;
            op[j] = o;
        }
    }
}

extern "C" void kernel_launch(void* const* d_in, const int* in_sizes, int n_in,
                              void* d_out, int out_size, void* d_ws, size_t ws_size,
                              hipStream_t stream)
{
    const float* x    = (const float*)d_in[0];   // (64,256,56,56) f32
    const float* mask = (const float*)d_in[1];   // (64,256,50,50) f32
    float* out = (float*)d_out;

    // d_ws layout:
    //   [0, 8KB)    counts[2048] (u32), fully written by kernel 1
    //   [64KB, ..)  bitmap: 2048*448 u64 = 7.34 MB
    unsigned* counts = (unsigned*)d_ws;
    u64* bitmap = (u64*)((char*)d_ws + 65536);

    dropblock_dilate<<<NBLOCKS, 256, 0, stream>>>(mask, bitmap, counts);
    dropblock_scale<<<NBLOCKS, 256, 0, stream>>>(x, bitmap, counts, out);
}